// Round 5
// baseline (254.876 us; speedup 1.0000x reference)
//
#include <hip/hip_runtime.h>
#include <math.h>

#define CI   256
#define CO   256
#define HW   56
#define LQ   7
#define BETA 10.0f

typedef __attribute__((ext_vector_type(8)))  short short8;
typedef __attribute__((ext_vector_type(4)))  float f32x4;

__device__ __forceinline__ ushort f2bf(float f) {
    uint u = __float_as_uint(f);
    u += 0x7FFF + ((u >> 16) & 1);
    return (ushort)(u >> 16);
}

// ---------------- Kernel 1: soft-quantize weights -> packed bf16 ----------------
// W2 layout: [chunk 8][tap 9][kb 4][co 256][e 8] bf16  (k = chunk*32 + kb*8 + e)
__global__ __launch_bounds__(256) void quant_weights(const float* __restrict__ p_c,
                                                     const float* __restrict__ q_level,
                                                     short* __restrict__ W2) {
    int idx = blockIdx.x * 256 + threadIdx.x;  // (co*256+ci)*9 + t
    if (idx >= CO * CI * 9) return;
    int coci = idx / 9;
    int t = idx - coci * 9;
    int co = coci >> 8, ci = coci & 255;
    const float* p = p_c + (size_t)idx * LQ;
    float pv[LQ];
    float ss = 0.f;
#pragma unroll
    for (int l = 0; l < LQ; ++l) { pv[l] = p[l]; ss += pv[l] * pv[l]; }
    float inv = rsqrtf(ss) * BETA;
    float m = -1e30f;
#pragma unroll
    for (int l = 0; l < LQ; ++l) { pv[l] *= inv; m = fmaxf(m, pv[l]); }
    float den = 0.f, num = 0.f;
#pragma unroll
    for (int l = 0; l < LQ; ++l) {
        float e = expf(pv[l] - m);
        den += e;
        num += e * q_level[l];
    }
    int widx = ((((ci >> 5) * 9 + t) * 4 + ((ci >> 3) & 3)) * 2048) + co * 8 + (ci & 7);
    W2[widx] = (short)f2bf(num / den);
}

// ---------------- Pre-pass: NCHW f32 -> padded NHWC bf16, border fused ----------------
// x_t: [32][58][58][256] bf16, x_t[b][h+1][w+1][ci] = bf16(x[b][ci][h][w]), borders 0
__global__ __launch_bounds__(256) void prep_main(const float* __restrict__ x,
                                                 ushort* __restrict__ xt) {
    __shared__ ushort ld[256 * 60];
    const int tid = threadIdx.x;
    const int h = blockIdx.x;   // 0..55
    const int b = blockIdx.y;

    if (h == 0 || h == 55) {
        int rr = (h == 0) ? 0 : 57;
        size_t base = ((size_t)b * 58 + rr) * 58 * 256;
        uint4 z = {0, 0, 0, 0};
        for (int i = tid; i < 58 * 256 / 8; i += 256)
            *(uint4*)&xt[base + (size_t)i * 8] = z;
    }
    if (tid < 64) {
        int col = (tid >> 5) * 57;
        int chk = tid & 31;
        size_t o = (((size_t)b * 58 + h + 1) * 58 + col) * 256 + chk * 8;
        uint4 z = {0, 0, 0, 0};
        *(uint4*)&xt[o] = z;
    }

    const float* xp = x + ((size_t)b * CI) * 3136 + h * HW;
#pragma unroll
    for (int s = 0; s < 14; ++s) {
        int flat = s * 1024 + tid * 4;
        int ci = flat / 56;
        int w  = flat - ci * 56;
        const float4 v = *(const float4*)(xp + (size_t)ci * 3136 + w);
        ushort4 o;
        o.x = f2bf(v.x); o.y = f2bf(v.y); o.z = f2bf(v.z); o.w = f2bf(v.w);
        *(ushort4*)&ld[ci * 60 + w] = o;
    }
    __syncthreads();
    const int w = tid & 63;
    const int wq = tid >> 6;
    if (w < 56) {
        size_t obase = (((size_t)b * 58 + h + 1) * 58 + (w + 1)) * 256;
#pragma unroll
        for (int s = 0; s < 8; ++s) {
            int cig = s * 4 + wq;
            int base = (cig * 8) * 60 + w;
            uint u0 = (uint)ld[base]       | ((uint)ld[base + 60]  << 16);
            uint u1 = (uint)ld[base + 120] | ((uint)ld[base + 180] << 16);
            uint u2 = (uint)ld[base + 240] | ((uint)ld[base + 300] << 16);
            uint u3 = (uint)ld[base + 360] | ((uint)ld[base + 420] << 16);
            uint4 o = {u0, u1, u2, u3};
            *(uint4*)&xt[obase + cig * 8] = o;
        }
    }
}

// ---------------- Kernel 2: 8-phase implicit-GEMM conv (T3+T4+T5) ----------------
// block: 512 thr = 8 waves; tile 256co x 256n (4h x 64w). wave: 64co x 128n
// (identical per-wave tile / LDS-read pattern to the proven 0-conflict r3 kernel).
// Per ci-chunk (K=32): 9 phases (one per tap): {8 ds_read_b128 B + prefetch next-tap
// A + <=1 stage glds; barrier; lgkm(0)+sched_barrier; setprio(1); 32 MFMA; setprio(0);
// barrier}. Tri-buffered LDS; stage(ch+2) issued taps 0-3; counted vmcnt at tap 8 only.
// Race invariants:
//  - buf[ch%3] fully written: its glds forced complete by vmcnt at (ch-1) tap 8 + barrier.
//  - glds to buf[(ch+2)%3] vs readers of chunk ch-1: all ds_reads of ch-1 are
//    lgkm(0)-waited inside their phase, before the chunk-crossing barrier.
__global__ __launch_bounds__(512, 2) void conv_mfma8(const ushort* __restrict__ xt_g,
                                                     const short* __restrict__ W2,
                                                     float* __restrict__ out) {
    __shared__ __align__(16) ushort xt[3][12672];  // 3 x 25344 B

    const int tid  = threadIdx.x;
    const int lane = tid & 63;
    const int wv   = tid >> 6;        // 0..7
    const int l15  = lane & 15;
    const int kb   = lane >> 4;       // 0..3 k-subgroup
    const int wm   = (wv >> 1) * 64;  // wave co offset (0,64,128,192)
    const int wn   = (wv & 1) * 2;    // wave row offset (0 or 2)

    const int h0 = blockIdx.x * 4;
    const int b  = blockIdx.z;

    // staging: 1584 granules of 16B, 198 per wave, 4 steps (64,64,64,6 lanes)
    int src_off[4];
#pragma unroll
    for (int s = 0; s < 4; ++s) {
        int g = wv * 198 + s * 64 + lane;   // masked lanes never use it
        int kbq = g & 3, pos = g >> 2;
        int r = pos / 66, c = pos - r * 66;
        int cc = c < 58 ? c : 57;
        int cig = kbq ^ ((c >> 1) & 3);     // swizzle on global source (m173)
        src_off[s] = ((b * 58 + h0 + r) * 58 + cc) * 256 + cig * 8;
    }

    f32x4 acc[4][8];
#pragma unroll
    for (int a = 0; a < 4; ++a)
#pragma unroll
        for (int f = 0; f < 8; ++f) acc[a][f] = (f32x4){0.f, 0.f, 0.f, 0.f};

#define STAGE(CH2, S)                                                                \
    if ((S) < 3 || lane < 6)                                                         \
        __builtin_amdgcn_global_load_lds(                                            \
            (const __attribute__((address_space(1))) void*)(xt_g + (CH2) * 32 + src_off[S]), \
            (__attribute__((address_space(3))) void*)&xt[(CH2) % 3][(wv * 198 + (S) * 64) * 8], \
            16, 0, 0)

#define LOADA(DST, CH, T)                                                            \
    {                                                                                \
        const short* ap_ = W2 + (size_t)((((CH) * 9 + (T)) * 4 + kb) * 256 + wm + l15) * 8; \
        DST[0] = *(const short8*)ap_;                                                \
        DST[1] = *(const short8*)(ap_ + 128);                                        \
        DST[2] = *(const short8*)(ap_ + 256);                                        \
        DST[3] = *(const short8*)(ap_ + 384);                                        \
    }

    short8 afA[4], afB[4];

    // ---- prologue: stage chunks 0,1; load A(chunk0, tap0) ----
#pragma unroll
    for (int s = 0; s < 4; ++s) { STAGE(0, s); }
#pragma unroll
    for (int s = 0; s < 4; ++s) { STAGE(1, s); }
    __builtin_amdgcn_sched_barrier(0);
    LOADA(afA, 0, 0);
    __builtin_amdgcn_sched_barrier(0);
    asm volatile("s_waitcnt vmcnt(8)" ::: "memory");  // stage(0) landed
    __builtin_amdgcn_s_barrier();

    for (int ch = 0; ch < 8; ++ch) {
        const ushort* buf = xt[ch % 3];
#pragma unroll
        for (int t = 0; t < 9; ++t) {
            // --- phase t: issue loads ---
            const int kh = t / 3, kw = t - kh * 3;
            const int c0 = kw + l15;
            const int r0 = wn + kh;
            const ushort* bp = &buf[((r0 * 66 + c0) * 4 + (kb ^ ((c0 >> 1) & 3))) * 8];
            short8 bf[8];
#pragma unroll
            for (int f = 0; f < 8; ++f)
                bf[f] = *(const short8*)(bp + (f >> 2) * 2112 + (f & 3) * 512);

            if (t < 8) {
                LOADA(afB, ch, t + 1);
            } else if (ch < 7) {
                LOADA(afB, ch + 1, 0);
            }
            if (t < 4 && ch < 6) { STAGE(ch + 2, t); }
            if (t == 8) {
                if (ch < 6)       asm volatile("s_waitcnt vmcnt(8)" ::: "memory");  // stage(ch+1) done
                else if (ch == 6) asm volatile("s_waitcnt vmcnt(4)" ::: "memory");  // stage(7) done
            }
            __builtin_amdgcn_s_barrier();
            asm volatile("s_waitcnt lgkmcnt(0)" ::: "memory");
            __builtin_amdgcn_sched_barrier(0);  // rule #18: keep MFMA after the wait

            __builtin_amdgcn_s_setprio(1);
#pragma unroll
            for (int a = 0; a < 4; ++a)
#pragma unroll
                for (int f = 0; f < 8; ++f)
                    acc[a][f] = __builtin_amdgcn_mfma_f32_16x16x32_bf16(afA[a], bf[f], acc[a][f], 0, 0, 0);
            __builtin_amdgcn_s_setprio(0);
            __builtin_amdgcn_s_barrier();

            if (t < 8 || ch < 7) {  // rotate A ping-pong (odd tap count -> explicit copy)
                afA[0] = afB[0]; afA[1] = afB[1]; afA[2] = afB[2]; afA[3] = afB[3];
            }
        }
    }

    // ---- epilogue: D layout n=lane&15, m=(lane>>4)*4+j ----
#pragma unroll
    for (int a = 0; a < 4; ++a) {
#pragma unroll
        for (int f = 0; f < 8; ++f) {
            int wloc = (f & 3) * 16 + l15;
            if (wloc < HW) {
                int h = h0 + wn + (f >> 2);
#pragma unroll
                for (int j = 0; j < 4; ++j) {
                    int cog = wm + 16 * a + kb * 4 + j;
                    out[(((size_t)b * CO + cog) * HW + h) * HW + wloc] = acc[a][f][j];
                }
            }
        }
    }
#undef STAGE
#undef LOADA
}

// ---------------- Fallback (no-workspace path, round-2 verbatim) ----------------
__global__ __launch_bounds__(256, 2) void conv_mfma_fb(const float* __restrict__ x,
                                                       const short* __restrict__ W2,
                                                       float* __restrict__ out) {
    __shared__ __align__(16) short xs[6 * 72 * 32];

    const int tid  = threadIdx.x;
    const int lane = tid & 63;
    const int wv   = tid >> 6;
    const int l15  = lane & 15;
    const int kb   = lane >> 4;
    const int wm    = (wv >> 1) * 64;
    const int wnrow = (wv & 1) * 2;

    const int h0  = blockIdx.x * 4;
    const int co0 = blockIdx.y * 128;
    const int b   = blockIdx.z;

    f32x4 acc[4][8];
#pragma unroll
    for (int a = 0; a < 4; ++a)
#pragma unroll
        for (int f = 0; f < 8; ++f) acc[a][f] = (f32x4){0.f, 0.f, 0.f, 0.f};

    const float* xb = x + (size_t)b * CI * HW * HW;

    for (int ch = 0; ch < 8; ++ch) {
        const int ci0 = ch * 32;
        for (int f = tid; f < 6 * 66; f += 256) {
            int r = f / 66, c = f % 66;
            int h = h0 - 1 + r, wc = c - 1;
            bool valid = (h >= 0) & (h < HW) & (wc >= 0) & (wc < HW);
            const float* xsrc = xb + (size_t)ci0 * 3136 + (valid ? (h * HW + wc) : 0);
            int sw = (c >> 1) & 3;
            int sbase = (r * 72 + c) * 32;
#pragma unroll
            for (int k = 0; k < 4; ++k) {
                short8 pk;
#pragma unroll
                for (int e = 0; e < 8; ++e) {
                    float v = xsrc[(size_t)(k * 8 + e) * 3136];
                    pk[e] = (short)f2bf(valid ? v : 0.f);
                }
                *(short8*)&xs[sbase + ((k ^ sw) * 8)] = pk;
            }
        }
        __syncthreads();

#pragma unroll
        for (int kh = 0; kh < 3; ++kh) {
#pragma unroll
            for (int kw = 0; kw < 3; ++kw) {
                const int t = kh * 3 + kw;
                const short* ap = W2 + (size_t)((((ch * 9 + t) * 4 + kb) * 256) + co0 + wm + l15) * 8;
                short8 af[4];
#pragma unroll
                for (int a = 0; a < 4; ++a) af[a] = *(const short8*)(ap + a * 128);

                const int c0 = kw + l15;
                const int r0 = wnrow + kh;
                const short* bp = &xs[(r0 * 72 + c0) * 32 + ((kb ^ ((c0 >> 1) & 3)) * 8)];
                short8 bf[8];
#pragma unroll
                for (int f = 0; f < 8; ++f)
                    bf[f] = *(const short8*)(bp + (f >> 2) * 2304 + (f & 3) * 512);

#pragma unroll
                for (int a = 0; a < 4; ++a)
#pragma unroll
                    for (int f = 0; f < 8; ++f)
                        acc[a][f] = __builtin_amdgcn_mfma_f32_16x16x32_bf16(af[a], bf[f], acc[a][f], 0, 0, 0);
            }
        }
        __syncthreads();
    }

#pragma unroll
    for (int a = 0; a < 4; ++a) {
#pragma unroll
        for (int f = 0; f < 8; ++f) {
            int wloc = (f & 3) * 16 + l15;
            if (wloc < HW) {
                int h = h0 + wnrow + (f >> 2);
#pragma unroll
                for (int j = 0; j < 4; ++j) {
                    int cog = co0 + wm + 16 * a + kb * 4 + j;
                    out[(((size_t)b * CO + cog) * HW + h) * HW + wloc] = acc[a][f][j];
                }
            }
        }
    }
}

extern "C" void kernel_launch(void* const* d_in, const int* in_sizes, int n_in,
                              void* d_out, int out_size, void* d_ws, size_t ws_size,
                              hipStream_t stream) {
    const float* x       = (const float*)d_in[0]; // (32,256,56,56)
    const float* p_c     = (const float*)d_in[1]; // (256,256,3,3,7)
    const float* q_level = (const float*)d_in[2]; // (7,)
    float* out = (float*)d_out;

    short* W2 = (short*)d_ws;                          // 1.18 MB at offset 0
    const size_t XT_OFF = 2u * 1024 * 1024;
    const size_t need = XT_OFF + (size_t)32 * 3364 * 256 * 2;  // + 55.1 MB NHWC bf16

    quant_weights<<<(CO * CI * 9 + 255) / 256, 256, 0, stream>>>(p_c, q_level, W2);

    if (ws_size >= need) {
        ushort* xt_g = (ushort*)((char*)d_ws + XT_OFF);
        prep_main<<<dim3(56, 32), 256, 0, stream>>>(x, xt_g);
        conv_mfma8<<<dim3(14, 1, 32), 512, 0, stream>>>(xt_g, W2, out);
    } else {
        conv_mfma_fb<<<dim3(14, 2, 32), 256, 0, stream>>>(x, W2, out);
    }
}

// Round 6
// 210.258 us; speedup vs baseline: 1.2122x; 1.2122x over previous
//
#include <hip/hip_runtime.h>
#include <math.h>

#define CI   256
#define CO   256
#define HW   56
#define LQ   7
#define BETA 10.0f

typedef __attribute__((ext_vector_type(8)))  short short8;
typedef __attribute__((ext_vector_type(4)))  float f32x4;

__device__ __forceinline__ ushort f2bf(float f) {
    uint u = __float_as_uint(f);
    u += 0x7FFF + ((u >> 16) & 1);
    return (ushort)(u >> 16);
}

#define GLDS(SRC, DST)                                                        \
    __builtin_amdgcn_global_load_lds(                                         \
        (const __attribute__((address_space(1))) void*)(SRC),                 \
        (__attribute__((address_space(3))) void*)(DST), 16, 0, 0)

// ---------------- Kernel 1: soft-quantize weights -> packed bf16 ----------------
// W2 layout: [chunk 8][tap 9][kb 4][co 256][e 8] bf16  (k = chunk*32 + kb*8 + e)
__global__ __launch_bounds__(256) void quant_weights(const float* __restrict__ p_c,
                                                     const float* __restrict__ q_level,
                                                     short* __restrict__ W2) {
    int idx = blockIdx.x * 256 + threadIdx.x;  // (co*256+ci)*9 + t
    if (idx >= CO * CI * 9) return;
    int coci = idx / 9;
    int t = idx - coci * 9;
    int co = coci >> 8, ci = coci & 255;
    const float* p = p_c + (size_t)idx * LQ;
    float pv[LQ];
    float ss = 0.f;
#pragma unroll
    for (int l = 0; l < LQ; ++l) { pv[l] = p[l]; ss += pv[l] * pv[l]; }
    float inv = rsqrtf(ss) * BETA;
    float m = -1e30f;
#pragma unroll
    for (int l = 0; l < LQ; ++l) { pv[l] *= inv; m = fmaxf(m, pv[l]); }
    float den = 0.f, num = 0.f;
#pragma unroll
    for (int l = 0; l < LQ; ++l) {
        float e = expf(pv[l] - m);
        den += e;
        num += e * q_level[l];
    }
    int widx = ((((ci >> 5) * 9 + t) * 4 + ((ci >> 3) & 3)) * 2048) + co * 8 + (ci & 7);
    W2[widx] = (short)f2bf(num / den);
}

// ---------------- Pre-pass: NCHW f32 -> padded NHWC bf16, border fused ----------------
__global__ __launch_bounds__(256) void prep_main(const float* __restrict__ x,
                                                 ushort* __restrict__ xt) {
    __shared__ ushort ld[256 * 60];
    const int tid = threadIdx.x;
    const int h = blockIdx.x;   // 0..55
    const int b = blockIdx.y;

    if (h == 0 || h == 55) {
        int rr = (h == 0) ? 0 : 57;
        size_t base = ((size_t)b * 58 + rr) * 58 * 256;
        uint4 z = {0, 0, 0, 0};
        for (int i = tid; i < 58 * 256 / 8; i += 256)
            *(uint4*)&xt[base + (size_t)i * 8] = z;
    }
    if (tid < 64) {
        int col = (tid >> 5) * 57;
        int chk = tid & 31;
        size_t o = (((size_t)b * 58 + h + 1) * 58 + col) * 256 + chk * 8;
        uint4 z = {0, 0, 0, 0};
        *(uint4*)&xt[o] = z;
    }

    const float* xp = x + ((size_t)b * CI) * 3136 + h * HW;
#pragma unroll
    for (int s = 0; s < 14; ++s) {
        int flat = s * 1024 + tid * 4;
        int ci = flat / 56;
        int w  = flat - ci * 56;
        const float4 v = *(const float4*)(xp + (size_t)ci * 3136 + w);
        ushort4 o;
        o.x = f2bf(v.x); o.y = f2bf(v.y); o.z = f2bf(v.z); o.w = f2bf(v.w);
        *(ushort4*)&ld[ci * 60 + w] = o;
    }
    __syncthreads();
    const int w = tid & 63;
    const int wq = tid >> 6;
    if (w < 56) {
        size_t obase = (((size_t)b * 58 + h + 1) * 58 + (w + 1)) * 256;
#pragma unroll
        for (int s = 0; s < 8; ++s) {
            int cig = s * 4 + wq;
            int base = (cig * 8) * 60 + w;
            uint u0 = (uint)ld[base]       | ((uint)ld[base + 60]  << 16);
            uint u1 = (uint)ld[base + 120] | ((uint)ld[base + 180] << 16);
            uint u2 = (uint)ld[base + 240] | ((uint)ld[base + 300] << 16);
            uint u3 = (uint)ld[base + 360] | ((uint)ld[base + 420] << 16);
            uint4 o = {u0, u1, u2, u3};
            *(uint4*)&xt[obase + cig * 8] = o;
        }
    }
}

// ---------------- Kernel 2: per-tap-phase implicit-GEMM conv ----------------
// 256 thr = 4 waves; block tile 128co x 256n (4h x 64w); wave 64co x 128n
// (r3's exact fragment/read patterns). ALL global traffic via global_load_lds:
//  - B (x): per-chunk double buffer (25344B x2), 7 granule-insts/wave spread 1/tap
//  - A (W): per-tap ring of 3 slots (8192B each), staged 2 taps ahead, 2 insts/wave/tap
// Counted vmcnt per phase: N = 2 + b_t + b_{t-1}  (4 mid, 3 at t=0/7, 2 at t=8);
// phantom clamped issues at the tail keep counts uniform. vmcnt NEVER drains to 0
// in the loop; no register global loads anywhere in the K-loop.
__global__ __launch_bounds__(256, 2) void conv_p9(const ushort* __restrict__ xt_g,
                                                  const short* __restrict__ W2,
                                                  float* __restrict__ out) {
    __shared__ __align__(16) ushort Bb[2][12672];  // 2 x 25344 B
    __shared__ __align__(16) ushort Ab[3][4096];   // 3 x 8192 B

    const int tid  = threadIdx.x;
    const int lane = tid & 63;
    const int wv   = tid >> 6;
    const int l15  = lane & 15;
    const int kb   = lane >> 4;
    const int wm   = (wv >> 1) * 64;
    const int wn   = (wv & 1) * 2;

    const int h0  = blockIdx.x * 4;
    const int co0 = blockIdx.y * 128;
    const int b   = blockIdx.z;

    // B staging source offsets (1584 granules, 396/wave, 7 insts/wave/chunk)
    int bsrc[7];
#pragma unroll
    for (int s = 0; s < 7; ++s) {
        int gl = s * 64 + lane;
        int g  = wv * 396 + (gl < 396 ? gl : 0);
        int kbq = g & 3, pos = g >> 2;
        int r = pos / 66, c = pos - r * 66;
        int cc = c < 58 ? c : 57;
        int cig = kbq ^ ((c >> 1) & 3);     // swizzle on global source (m173)
        bsrc[s] = ((b * 58 + h0 + r) * 58 + cc) * 256 + cig * 8;
    }
    // A staging source offsets (512 granules/tap, 128/wave, 2 insts/wave/tap)
    int asrc[2];
#pragma unroll
    for (int s = 0; s < 2; ++s) {
        int g = wv * 128 + s * 64 + lane;
        asrc[s] = ((g >> 7) * 256 + co0 + (g & 127)) * 8;
    }

    f32x4 acc[4][8];
#pragma unroll
    for (int a = 0; a < 4; ++a)
#pragma unroll
        for (int f = 0; f < 8; ++f) acc[a][f] = (f32x4){0.f, 0.f, 0.f, 0.f};

    // ---- prologue: B(0) -> Bb[0]; A taps 0,1 -> slots 0,1 ----
#pragma unroll
    for (int s = 0; s < 7; ++s) {
        if (s * 64 + lane < 396)
            GLDS(xt_g + bsrc[s], &Bb[0][(wv * 396 + s * 64) * 8]);
    }
#pragma unroll
    for (int s = 0; s < 2; ++s) GLDS(W2 + asrc[s], &Ab[0][(wv * 128 + s * 64) * 8]);
#pragma unroll
    for (int s = 0; s < 2; ++s) GLDS(W2 + 8192 + asrc[s], &Ab[1][(wv * 128 + s * 64) * 8]);
    asm volatile("s_waitcnt vmcnt(0)" ::: "memory");
    __builtin_amdgcn_s_barrier();

    for (int ch = 0; ch < 8; ++ch) {
        const ushort* bufB = Bb[ch & 1];
        ushort* nextB = Bb[(ch + 1) & 1];
        const int chb = (ch < 7 ? ch + 1 : 7) * 32;     // phantom re-stage at tail
#pragma unroll
        for (int t = 0; t < 9; ++t) {
            // -- step 1: ds_read A(t) + B(t) fragments --
            const ushort* abuf = Ab[t % 3];
            short8 af[4];
#pragma unroll
            for (int a = 0; a < 4; ++a)
                af[a] = *(const short8*)&abuf[(kb * 128 + wm + 16 * a + l15) * 8];

            const int kh = t / 3, kw = t - kh * 3;
            const int c0 = kw + l15;
            const int r0 = wn + kh;
            const ushort* bp = &bufB[((r0 * 66 + c0) * 4 + (kb ^ ((c0 >> 1) & 3))) * 8];
            short8 bf[8];
#pragma unroll
            for (int f = 0; f < 8; ++f)
                bf[f] = *(const short8*)(bp + (f >> 2) * 2112 + (f & 3) * 512);

            // -- step 2: issue glds (A 2 ops, then B 0/1 op) --
            int g2 = ch * 9 + t + 2;
            if (g2 > 71) g2 = 71;                        // phantom at tail
            ushort* aslot = Ab[(t + 2) % 3];
            GLDS(W2 + (size_t)g2 * 8192 + asrc[0], &aslot[(wv * 128) * 8]);
            GLDS(W2 + (size_t)g2 * 8192 + asrc[1], &aslot[(wv * 128 + 64) * 8]);
            if (t < 7) {
                if (t * 64 + lane < 396)
                    GLDS(xt_g + chb + bsrc[t], &nextB[(wv * 396 + t * 64) * 8]);
            }

            // -- step 3: counted vmcnt (A(t+1) landed; chunk-end also covers B(ch+1)) --
            if (t == 0 || t == 7)
                asm volatile("s_waitcnt vmcnt(3)" ::: "memory");
            else if (t == 8)
                asm volatile("s_waitcnt vmcnt(2)" ::: "memory");
            else
                asm volatile("s_waitcnt vmcnt(4)" ::: "memory");
            // -- step 4: cross-wave visibility of staged data --
            __builtin_amdgcn_s_barrier();
            // -- step 5: my ds_reads complete; pin MFMA below (rule #18) --
            asm volatile("s_waitcnt lgkmcnt(0)" ::: "memory");
            __builtin_amdgcn_sched_barrier(0);

            // -- step 6: MFMA cluster --
            __builtin_amdgcn_s_setprio(1);
#pragma unroll
            for (int a = 0; a < 4; ++a)
#pragma unroll
                for (int f = 0; f < 8; ++f)
                    acc[a][f] = __builtin_amdgcn_mfma_f32_16x16x32_bf16(af[a], bf[f], acc[a][f], 0, 0, 0);
            __builtin_amdgcn_s_setprio(0);
            // -- step 7: protect ring slot (t+2)%3 reuse --
            __builtin_amdgcn_s_barrier();
        }
    }

    // ---- epilogue: D layout n=lane&15, m=(lane>>4)*4+j ----
#pragma unroll
    for (int a = 0; a < 4; ++a) {
#pragma unroll
        for (int f = 0; f < 8; ++f) {
            int wloc = (f & 3) * 16 + l15;
            if (wloc < HW) {
                int h = h0 + wn + (f >> 2);
#pragma unroll
                for (int j = 0; j < 4; ++j) {
                    int cog = co0 + wm + 16 * a + kb * 4 + j;
                    out[(((size_t)b * CO + cog) * HW + h) * HW + wloc] = acc[a][f][j];
                }
            }
        }
    }
}

// ---------------- Fallback (no-workspace path, round-2 verbatim) ----------------
__global__ __launch_bounds__(256, 2) void conv_mfma_fb(const float* __restrict__ x,
                                                       const short* __restrict__ W2,
                                                       float* __restrict__ out) {
    __shared__ __align__(16) short xs[6 * 72 * 32];

    const int tid  = threadIdx.x;
    const int lane = tid & 63;
    const int wv   = tid >> 6;
    const int l15  = lane & 15;
    const int kb   = lane >> 4;
    const int wm    = (wv >> 1) * 64;
    const int wnrow = (wv & 1) * 2;

    const int h0  = blockIdx.x * 4;
    const int co0 = blockIdx.y * 128;
    const int b   = blockIdx.z;

    f32x4 acc[4][8];
#pragma unroll
    for (int a = 0; a < 4; ++a)
#pragma unroll
        for (int f = 0; f < 8; ++f) acc[a][f] = (f32x4){0.f, 0.f, 0.f, 0.f};

    const float* xb = x + (size_t)b * CI * HW * HW;

    for (int ch = 0; ch < 8; ++ch) {
        const int ci0 = ch * 32;
        for (int f = tid; f < 6 * 66; f += 256) {
            int r = f / 66, c = f % 66;
            int h = h0 - 1 + r, wc = c - 1;
            bool valid = (h >= 0) & (h < HW) & (wc >= 0) & (wc < HW);
            const float* xsrc = xb + (size_t)ci0 * 3136 + (valid ? (h * HW + wc) : 0);
            int sw = (c >> 1) & 3;
            int sbase = (r * 72 + c) * 32;
#pragma unroll
            for (int k = 0; k < 4; ++k) {
                short8 pk;
#pragma unroll
                for (int e = 0; e < 8; ++e) {
                    float v = xsrc[(size_t)(k * 8 + e) * 3136];
                    pk[e] = (short)f2bf(valid ? v : 0.f);
                }
                *(short8*)&xs[sbase + ((k ^ sw) * 8)] = pk;
            }
        }
        __syncthreads();

#pragma unroll
        for (int kh = 0; kh < 3; ++kh) {
#pragma unroll
            for (int kw = 0; kw < 3; ++kw) {
                const int t = kh * 3 + kw;
                const short* ap = W2 + (size_t)((((ch * 9 + t) * 4 + kb) * 256) + co0 + wm + l15) * 8;
                short8 af[4];
#pragma unroll
                for (int a = 0; a < 4; ++a) af[a] = *(const short8*)(ap + a * 128);

                const int c0 = kw + l15;
                const int r0 = wnrow + kh;
                const short* bp = &xs[(r0 * 72 + c0) * 32 + ((kb ^ ((c0 >> 1) & 3)) * 8)];
                short8 bf[8];
#pragma unroll
                for (int f = 0; f < 8; ++f)
                    bf[f] = *(const short8*)(bp + (f >> 2) * 2304 + (f & 3) * 512);

#pragma unroll
                for (int a = 0; a < 4; ++a)
#pragma unroll
                    for (int f = 0; f < 8; ++f)
                        acc[a][f] = __builtin_amdgcn_mfma_f32_16x16x32_bf16(af[a], bf[f], acc[a][f], 0, 0, 0);
            }
        }
        __syncthreads();
    }

#pragma unroll
    for (int a = 0; a < 4; ++a) {
#pragma unroll
        for (int f = 0; f < 8; ++f) {
            int wloc = (f & 3) * 16 + l15;
            if (wloc < HW) {
                int h = h0 + wnrow + (f >> 2);
#pragma unroll
                for (int j = 0; j < 4; ++j) {
                    int cog = co0 + wm + 16 * a + kb * 4 + j;
                    out[(((size_t)b * CO + cog) * HW + h) * HW + wloc] = acc[a][f][j];
                }
            }
        }
    }
}

extern "C" void kernel_launch(void* const* d_in, const int* in_sizes, int n_in,
                              void* d_out, int out_size, void* d_ws, size_t ws_size,
                              hipStream_t stream) {
    const float* x       = (const float*)d_in[0]; // (32,256,56,56)
    const float* p_c     = (const float*)d_in[1]; // (256,256,3,3,7)
    const float* q_level = (const float*)d_in[2]; // (7,)
    float* out = (float*)d_out;

    short* W2 = (short*)d_ws;                          // 1.18 MB at offset 0
    const size_t XT_OFF = 2u * 1024 * 1024;
    const size_t need = XT_OFF + (size_t)32 * 3364 * 256 * 2;  // + 55.1 MB NHWC bf16

    quant_weights<<<(CO * CI * 9 + 255) / 256, 256, 0, stream>>>(p_c, q_level, W2);

    if (ws_size >= need) {
        ushort* xt_g = (ushort*)((char*)d_ws + XT_OFF);
        prep_main<<<dim3(56, 32), 256, 0, stream>>>(x, xt_g);
        conv_p9<<<dim3(14, 2, 32), 256, 0, stream>>>(xt_g, W2, out);
    } else {
        conv_mfma_fb<<<dim3(14, 2, 32), 256, 0, stream>>>(x, W2, out);
    }
}